// Round 4
// baseline (476.887 us; speedup 1.0000x reference)
//
#include <hip/hip_runtime.h>
#include <math.h>

#define N_PTS 1024
#define BATCH 8
#define KNN 20
#define EPSB 1e-5f
#define SLOPE 0.2f

typedef __attribute__((ext_vector_type(8))) short short8;
typedef __attribute__((ext_vector_type(4))) float f32x4;
typedef unsigned short ushort_t;
typedef unsigned long long u64;

__device__ __forceinline__ float lrelu(float y) { return y > 0.f ? y : SLOPE * y; }

__device__ __forceinline__ ushort_t f2bf(float f) {
    union { float f; unsigned u; } v; v.f = f;
    unsigned r = v.u + 0x7FFF + ((v.u >> 16) & 1);   // RNE
    return (ushort_t)(r >> 16);
}

// ---------------- fused weight prep: we->bf16 + 4x W' transforms ----------------
__device__ __forceinline__ void wprep_one(const float* __restrict__ w, float* __restrict__ wpt,
                                          int C, int Cout, int g) {
    int M2 = 2 * Cout;
    if (g >= C * M2) return;
    int c = g / M2, m = g - c * M2;
    float v;
    if (m < Cout) v = w[(size_t)m * 2 * C + c];
    else { int o = m - Cout; v = w[(size_t)o * 2 * C + C + c] - w[(size_t)o * 2 * C + c]; }
    wpt[(size_t)c * M2 + m] = v;
}

__global__ void prep_kernel(const float* __restrict__ we, ushort_t* __restrict__ weh,
                            const float* __restrict__ w0, float* __restrict__ wpt0,
                            const float* __restrict__ w1, float* __restrict__ wpt1,
                            const float* __restrict__ w2, float* __restrict__ wpt2,
                            const float* __restrict__ w3, float* __restrict__ wpt3) {
    int bx = blockIdx.x, tid = threadIdx.x;
    if (bx < 512) {
        int g = bx * 256 + tid;               // 131072 float4 of we
        float4 v = ((const float4*)we)[g];
        ushort4 o;
        o.x = f2bf(v.x); o.y = f2bf(v.y); o.z = f2bf(v.z); o.w = f2bf(v.w);
        ((ushort4*)weh)[g] = o;
    } else if (bx < 514) {
        wprep_one(w0, wpt0, 3, 64, (bx - 512) * 256 + tid);
    } else if (bx < 546) {
        wprep_one(w1, wpt1, 64, 64, (bx - 514) * 256 + tid);
    } else if (bx < 610) {
        wprep_one(w2, wpt2, 64, 128, (bx - 546) * 256 + tid);
    } else {
        wprep_one(w3, wpt3, 128, 256, (bx - 610) * 256 + tid);
    }
}

// ---------------- xx[b][n] = sum_c x^2 (same summation order as inline version) ----------------
__global__ void __launch_bounds__(64)
xx_kernel(const float* __restrict__ x, float* __restrict__ xx, int C, int bstride) {
    int b = blockIdx.y;
    int n = blockIdx.x * 64 + threadIdx.x;
    const float* xb = x + (size_t)b * bstride + n;
    float s = 0.f;
    #pragma unroll 4
    for (int c = 0; c < C; c++) { float v = xb[(size_t)c * N_PTS]; s += v * v; }
    xx[b * N_PTS + n] = s;
}

// ---------------- fused pd' + abv, double-buffered staging ----------------
// bx < 8 : pd tile  (m0 = bx*128)      pd'[b,n,m] = 2*dot - xx[m]   (row term dropped:
//          constant per row -> top-k invariant)
// bx >= 8: abv tile (m0 = (bx-8)*128)  [A;Bv] = W' * x
// One barrier per K-chunk: issue chunk c+1 global loads -> compute chunk c from
// buf[cur] -> ds_write chunk c+1 into buf[cur^1] -> barrier. Load latency hides
// under ~2048 cy of FMA issue.
__global__ void __launch_bounds__(256)
pdabv_kernel(const float* __restrict__ x, const float* __restrict__ wpt,
             const float* __restrict__ xx,
             float* __restrict__ pd, float* __restrict__ A, float* __restrict__ Bv,
             int C, int Cout, int bstride) {
    int b = blockIdx.z;
    int nt = blockIdx.y;
    int bx = blockIdx.x;
    int tid = threadIdx.x;
    int tx = tid & 15, ty = tid >> 4;
    int n0 = nt * 128;
    __shared__ float sU0[2][16][128];
    __shared__ float sU1[2][16][128];
    const float* xb = x + (size_t)b * bstride;

    const float* p0; const float* p1; int s0, s1, m0;
    if (bx < 8) { m0 = bx * 128;       p0 = xb + n0;  p1 = xb + m0; s0 = N_PTS;    s1 = N_PTS; }
    else        { m0 = (bx - 8) * 128; p0 = wpt + m0; p1 = xb + n0; s0 = 2 * Cout; s1 = N_PTS; }

    float acc[8][8] = {};
    float4 r0[2], r1[2];
    int fr0 = tid >> 5, fr1 = (256 + tid) >> 5;          // staging rows (0..15)
    int fc = (tid & 31) * 4;                             // staging col

    // prologue: chunk 0
    {
        float4 z = {0.f, 0.f, 0.f, 0.f};
        r0[0] = (fr0 < C) ? *(const float4*)&p0[(size_t)fr0 * s0 + fc] : z;
        r1[0] = (fr0 < C) ? *(const float4*)&p1[(size_t)fr0 * s1 + fc] : z;
        r0[1] = (fr1 < C) ? *(const float4*)&p0[(size_t)fr1 * s0 + fc] : z;
        r1[1] = (fr1 < C) ? *(const float4*)&p1[(size_t)fr1 * s1 + fc] : z;
        *(float4*)&sU0[0][fr0][fc] = r0[0];
        *(float4*)&sU1[0][fr0][fc] = r1[0];
        *(float4*)&sU0[0][fr1][fc] = r0[1];
        *(float4*)&sU1[0][fr1][fc] = r1[1];
    }
    __syncthreads();

    int nc = (C + 15) >> 4;
    for (int cc = 0; cc < nc; cc++) {
        int cur = cc & 1;
        if (cc + 1 < nc) {
            int c0 = (cc + 1) * 16;
            float4 z = {0.f, 0.f, 0.f, 0.f};
            int ca = c0 + fr0, cb = c0 + fr1;
            r0[0] = (ca < C) ? *(const float4*)&p0[(size_t)ca * s0 + fc] : z;
            r1[0] = (ca < C) ? *(const float4*)&p1[(size_t)ca * s1 + fc] : z;
            r0[1] = (cb < C) ? *(const float4*)&p0[(size_t)cb * s0 + fc] : z;
            r1[1] = (cb < C) ? *(const float4*)&p1[(size_t)cb * s1 + fc] : z;
        }
        int kmax = C - cc * 16; if (kmax > 16) kmax = 16;
        if (kmax == 16) {
            #pragma unroll
            for (int k = 0; k < 16; k++) {
                float4 a0 = *(const float4*)&sU0[cur][k][ty * 4];
                float4 a1 = *(const float4*)&sU0[cur][k][64 + ty * 4];
                float4 b0 = *(const float4*)&sU1[cur][k][tx * 4];
                float4 b1 = *(const float4*)&sU1[cur][k][64 + tx * 4];
                float av[8] = {a0.x, a0.y, a0.z, a0.w, a1.x, a1.y, a1.z, a1.w};
                float bw[8] = {b0.x, b0.y, b0.z, b0.w, b1.x, b1.y, b1.z, b1.w};
                #pragma unroll
                for (int i = 0; i < 8; i++)
                    #pragma unroll
                    for (int j = 0; j < 8; j++) acc[i][j] += av[i] * bw[j];
            }
        } else {
            for (int k = 0; k < kmax; k++) {
                float4 a0 = *(const float4*)&sU0[cur][k][ty * 4];
                float4 a1 = *(const float4*)&sU0[cur][k][64 + ty * 4];
                float4 b0 = *(const float4*)&sU1[cur][k][tx * 4];
                float4 b1 = *(const float4*)&sU1[cur][k][64 + tx * 4];
                float av[8] = {a0.x, a0.y, a0.z, a0.w, a1.x, a1.y, a1.z, a1.w};
                float bw[8] = {b0.x, b0.y, b0.z, b0.w, b1.x, b1.y, b1.z, b1.w};
                #pragma unroll
                for (int i = 0; i < 8; i++)
                    #pragma unroll
                    for (int j = 0; j < 8; j++) acc[i][j] += av[i] * bw[j];
            }
        }
        if (cc + 1 < nc) {
            int nb = cur ^ 1;
            *(float4*)&sU0[nb][fr0][fc] = r0[0];
            *(float4*)&sU1[nb][fr0][fc] = r1[0];
            *(float4*)&sU0[nb][fr1][fc] = r0[1];
            *(float4*)&sU1[nb][fr1][fc] = r1[1];
        }
        __syncthreads();
    }

    if (bx < 8) {
        float xm[8];
        const float* xxb = xx + b * N_PTS + m0;
        *(float4*)&xm[0] = *(const float4*)&xxb[tx * 4];
        *(float4*)&xm[4] = *(const float4*)&xxb[64 + tx * 4];
        #pragma unroll
        for (int i = 0; i < 8; i++) {
            int n = n0 + (i >> 2) * 64 + ty * 4 + (i & 3);
            float* prow = pd + ((size_t)(b * N_PTS + n)) * N_PTS + m0;
            for (int jh = 0; jh < 2; jh++) {
                float4 o;
                o.x = 2.f * acc[i][jh * 4 + 0] - xm[jh * 4 + 0];
                o.y = 2.f * acc[i][jh * 4 + 1] - xm[jh * 4 + 1];
                o.z = 2.f * acc[i][jh * 4 + 2] - xm[jh * 4 + 2];
                o.w = 2.f * acc[i][jh * 4 + 3] - xm[jh * 4 + 3];
                *(float4*)&prow[jh * 64 + tx * 4] = o;
            }
        }
    } else {
        #pragma unroll
        for (int i = 0; i < 8; i++) {
            int rowm = m0 + (i >> 2) * 64 + ty * 4 + (i & 3);
            float* dst = (rowm < Cout) ? (A + ((size_t)b * Cout + rowm) * N_PTS)
                                       : (Bv + ((size_t)b * Cout + rowm - Cout) * N_PTS);
            for (int jh = 0; jh < 2; jh++) {
                float4 o;
                o.x = acc[i][jh * 4 + 0];
                o.y = acc[i][jh * 4 + 1];
                o.z = acc[i][jh * 4 + 2];
                o.w = acc[i][jh * 4 + 3];
                *(float4*)&dst[n0 + jh * 64 + tx * 4] = o;
            }
        }
    }
}

// ---------------- top-20 per row: threshold-compact + bitonic select (round-0 verbatim) ----------------
__global__ void __launch_bounds__(256)
topk_kernel(const float* __restrict__ pd, int* __restrict__ idx) {
    int wid = threadIdx.x >> 6;
    int row = blockIdx.x * 4 + wid;          // row = b*N + n
    int lane = threadIdx.x & 63;
    __shared__ u64 Sk[4][64];
    const float* p = pd + (size_t)row * N_PTS;
    float v[16];
    for (int q = 0; q < 4; q++) {
        float4 t = *(const float4*)&p[lane * 16 + q * 4];
        v[q * 4 + 0] = t.x; v[q * 4 + 1] = t.y; v[q * 4 + 2] = t.z; v[q * 4 + 3] = t.w;
    }
    float lmax = v[0];
    #pragma unroll
    for (int j = 1; j < 16; j++) lmax = fmaxf(lmax, v[j]);
    float s = lmax;
    #pragma unroll
    for (int k = 2; k <= 64; k <<= 1) {
        #pragma unroll
        for (int j = k >> 1; j > 0; j >>= 1) {
            float o = __shfl_xor(s, j, 64);
            bool takeMin = (((lane & k) == 0) == ((lane & j) == 0));
            float mn = fminf(s, o), mx = fmaxf(s, o);
            s = takeMin ? mn : mx;
        }
    }
    float tp = __shfl(s, 44, 64);            // 20th largest lane-max
    unsigned hm = 0;
    #pragma unroll
    for (int j = 0; j < 16; j++) hm |= (v[j] >= tp ? 1u : 0u) << j;
    int cnt = __popc(hm);
    int incl = cnt;
    #pragma unroll
    for (int d = 1; d < 64; d <<= 1) {
        int o = __shfl_up(incl, d, 64);
        if (lane >= d) incl += o;
    }
    int total = __shfl(incl, 63, 64);
    int pos = incl - cnt;
    if (total <= 64) {
        #pragma unroll
        for (int j = 0; j < 16; j++) {
            if (hm & (1u << j)) {
                unsigned u = __float_as_uint(v[j]);
                unsigned msk = ((unsigned)((int)u >> 31)) | 0x80000000u;
                Sk[wid][pos] = ((u64)(u ^ msk) << 32) | (unsigned)(1023 - (lane * 16 + j));
                pos++;
            }
        }
        u64 key = (lane < total) ? Sk[wid][lane] : 0ull;
        #pragma unroll
        for (int k = 2; k <= 64; k <<= 1) {
            #pragma unroll
            for (int j = k >> 1; j > 0; j >>= 1) {
                u64 o = __shfl_xor(key, j, 64);
                bool takeMin = (((lane & k) == 0) == ((lane & j) == 0));
                bool sgt = key > o;
                key = (sgt != takeMin) ? key : o;
            }
        }
        if (lane >= 44) {
            int m = 1023 - (int)(unsigned)(key & 0xFFFFFFFFu);
            idx[row * KNN + (63 - lane)] = m;
        }
    } else {
        for (int kk = 0; kk < KNN; kk++) {
            float bv = v[0]; int bj = 0;
            #pragma unroll
            for (int j = 1; j < 16; j++) if (v[j] > bv) { bv = v[j]; bj = j; }
            int bi = lane * 16 + bj;
            for (int d = 32; d > 0; d >>= 1) {
                float ov = __shfl_down(bv, d, 64);
                int oi = __shfl_down(bi, d, 64);
                if (ov > bv || (ov == bv && oi < bi)) { bv = ov; bi = oi; }
            }
            bi = __shfl(bi, 0, 64);
            if ((bi >> 4) == lane) {
                #pragma unroll
                for (int j = 0; j < 16; j++) if (j == (bi & 15)) v[j] = -INFINITY;
            }
            if (lane == 0) idx[row * KNN + kk] = bi;
        }
    }
}

// ---------------- gmax: LDS-staged gather-max + BN + lrelu ----------------
__global__ void __launch_bounds__(256)
gmax_kernel(const float* __restrict__ A, const float* __restrict__ Bv,
            const int* __restrict__ idx, const float* __restrict__ bnp,
            float* __restrict__ out, int Cout, int outStrideB) {
    int b = blockIdx.z;
    int n0 = blockIdx.x * 64;
    int o0 = blockIdx.y * 4;
    int tid = threadIdx.x;
    __shared__ int sidx[64 * 21];
    __shared__ float sA[4][N_PTS];
    for (int t = tid; t < 64 * KNN; t += 256) {
        int nl = t / KNN, k = t - nl * KNN;
        sidx[nl * 21 + k] = idx[(b * N_PTS + n0) * KNN + t];
    }
    const float* Abase = A + ((size_t)b * Cout + o0) * N_PTS;
    for (int q = 0; q < 4; q++) {
        int f = q * 256 + tid;                 // 1024 float4
        int r = f >> 8, c4 = (f & 255) * 4;
        *(float4*)&sA[r][c4] = *(const float4*)&Abase[(size_t)r * N_PTS + c4];
    }
    __syncthreads();
    int nl = tid & 63, ol = tid >> 6;
    float best = -INFINITY;
    #pragma unroll
    for (int k = 0; k < KNN; k++) {
        int j = sidx[nl * 21 + k];
        best = fmaxf(best, sA[ol][j]);
    }
    int o = o0 + ol;
    int n = n0 + nl;
    float pre = best + Bv[((size_t)b * Cout + o) * N_PTS + n];
    float g = bnp[o], bb = bnp[Cout + o], m = bnp[2 * Cout + o], vv = bnp[3 * Cout + o];
    float scale = g / sqrtf(vv + EPSB);
    out[(size_t)b * outStrideB + (size_t)o * N_PTS + n] = lrelu((pre - m) * scale + bb);
}

// ---------------- cat fp32 [b][c][n] -> catT bf16 [b][n][c] ----------------
__global__ void catT_kernel(const float* __restrict__ cat, ushort_t* __restrict__ catT) {
    int b = blockIdx.z, ct = blockIdx.y, nt = blockIdx.x;
    int tid = threadIdx.x;
    __shared__ float tile[64][65];
    const float* cb = cat + (size_t)b * 512 * N_PTS;
    for (int q = 0; q < 16; q++) {
        int e = q * 256 + tid;
        int c = e >> 6, n = e & 63;
        tile[c][n] = cb[(size_t)(ct * 64 + c) * N_PTS + nt * 64 + n];
    }
    __syncthreads();
    for (int q = 0; q < 16; q++) {
        int e = q * 256 + tid;
        int n = e >> 6, c = e & 63;
        catT[((size_t)b * N_PTS + nt * 64 + n) * 512 + ct * 64 + c] = f2bf(tile[c][n]);
    }
}

// ---------------- embedding GEMM (bf16 MFMA) + bn + lrelu + fused max/sum ----------------
__global__ void __launch_bounds__(256)
gemm6_mfma(const ushort_t* __restrict__ weh, const ushort_t* __restrict__ catT,
           const float* __restrict__ bne,
           float* __restrict__ pmax, float* __restrict__ psum) {
    int b = blockIdx.z, ot = blockIdx.y, nt = blockIdx.x;
    int tid = threadIdx.x;
    int w = tid >> 6, lane = tid & 63, q = lane >> 4, lr = lane & 15;
    int mblk = w >> 1, nblk = w & 1;
    __shared__ __align__(16) ushort_t sA[128 * 40];
    __shared__ __align__(16) ushort_t sB[128 * 40];
    __shared__ float sa[128], sc[128];
    __shared__ float redmax[128][2], redsum[128][2];
    int o0 = ot * 128, n0 = nt * 128;
    if (tid < 128) {
        int o = o0 + tid;
        float g = bne[o], bb = bne[1024 + o], m = bne[2048 + o], vv = bne[3072 + o];
        float scale = g / sqrtf(vv + EPSB);
        sa[tid] = scale; sc[tid] = bb - m * scale;
    }
    f32x4 acc[4][4] = {};
    const ushort_t* cT = catT + (size_t)b * N_PTS * 512;
    int r0 = tid >> 2, s = tid & 3;
    for (int k0 = 0; k0 < 512; k0 += 32) {
        __syncthreads();
        for (int h = 0; h < 2; h++) {
            int r = r0 + h * 64;
            *(short8*)&sA[r * 40 + s * 8] = *(const short8*)(weh + (size_t)(o0 + r) * 512 + k0 + s * 8);
            *(short8*)&sB[r * 40 + s * 8] = *(const short8*)(cT  + (size_t)(n0 + r) * 512 + k0 + s * 8);
        }
        __syncthreads();
        short8 af[4], bfr[4];
        for (int mi = 0; mi < 4; mi++)
            af[mi] = *(const short8*)&sA[(mblk * 64 + mi * 16 + lr) * 40 + q * 8];
        for (int ni = 0; ni < 4; ni++)
            bfr[ni] = *(const short8*)&sB[(nblk * 64 + ni * 16 + lr) * 40 + q * 8];
        for (int mi = 0; mi < 4; mi++)
            for (int ni = 0; ni < 4; ni++)
                acc[mi][ni] = __builtin_amdgcn_mfma_f32_16x16x32_bf16(af[mi], bfr[ni], acc[mi][ni], 0, 0, 0);
    }
    for (int mi = 0; mi < 4; mi++) {
        for (int r = 0; r < 4; r++) {
            int row = mblk * 64 + mi * 16 + q * 4 + r;
            float a = sa[row], c = sc[row];
            float mx = -INFINITY, sm = 0.f;
            for (int ni = 0; ni < 4; ni++) {
                float y = lrelu(acc[mi][ni][r] * a + c);
                mx = fmaxf(mx, y); sm += y;
            }
            for (int msk = 1; msk < 16; msk <<= 1) {
                mx = fmaxf(mx, __shfl_xor(mx, msk, 16));
                sm += __shfl_xor(sm, msk, 16);
            }
            if (lr == 0) { redmax[row][nblk] = mx; redsum[row][nblk] = sm; }
        }
    }
    __syncthreads();
    if (tid < 128) {
        float mx = fmaxf(redmax[tid][0], redmax[tid][1]);
        float sm = redsum[tid][0] + redsum[tid][1];
        int o = o0 + tid;
        pmax[((size_t)(b * 1024 + o)) * 8 + nt] = mx;
        psum[((size_t)(b * 1024 + o)) * 8 + nt] = sm;
    }
}

__global__ void pool_reduce_kernel(const float* __restrict__ pmax, const float* __restrict__ psum,
                                   float* __restrict__ h0) {
    int g = blockIdx.x * 256 + threadIdx.x;  // b*1024 + o
    int b = g >> 10, o = g & 1023;
    float mx = -INFINITY, sm = 0.f;
    for (int t = 0; t < 8; t++) { mx = fmaxf(mx, pmax[g * 8 + t]); sm += psum[g * 8 + t]; }
    h0[(size_t)b * 2048 + o] = mx;
    h0[(size_t)b * 2048 + 1024 + o] = sm * (1.0f / 1024.0f);
}

// ---------------- FC: one wave per output ----------------
__global__ void fc_kernel(const float* __restrict__ in, const float* __restrict__ w,
                          const float* __restrict__ bnp, const float* __restrict__ bias,
                          float* __restrict__ out, int Cin, int Cout, int mode) {
    int blk = blockIdx.x;  // b*Cout + o
    int b = blk / Cout, o = blk % Cout;
    int lane = threadIdx.x;
    const float* inb = in + (size_t)b * Cin;
    const float* wo = w + (size_t)o * Cin;
    float acc = 0.f;
    for (int c = lane; c < Cin; c += 64) acc += inb[c] * wo[c];
    for (int s = 32; s > 0; s >>= 1) acc += __shfl_down(acc, s, 64);
    if (lane == 0) {
        float y = acc;
        if (mode == 0) {
            float g = bnp[o], bb = bnp[Cout + o], m = bnp[2 * Cout + o], vv = bnp[3 * Cout + o];
            y = lrelu((y - m) * (g / sqrtf(vv + EPSB)) + bb);
        } else {
            y += bias[o];
        }
        out[(size_t)b * Cout + o] = y;
    }
}

extern "C" void kernel_launch(void* const* d_in, const int* in_sizes, int n_in,
                              void* d_out, int out_size, void* d_ws, size_t ws_size,
                              hipStream_t stream) {
    const float* x    = (const float*)d_in[0];
    const float* w0   = (const float*)d_in[1];
    const float* w1   = (const float*)d_in[2];
    const float* w2   = (const float*)d_in[3];
    const float* w3   = (const float*)d_in[4];
    const float* bn0  = (const float*)d_in[5];
    const float* bn1  = (const float*)d_in[6];
    const float* bn2  = (const float*)d_in[7];
    const float* bn3  = (const float*)d_in[8];
    const float* we   = (const float*)d_in[9];
    const float* bne  = (const float*)d_in[10];
    const float* wf0  = (const float*)d_in[11];
    const float* bnf0 = (const float*)d_in[12];
    const float* wf1  = (const float*)d_in[13];
    const float* bnf1 = (const float*)d_in[14];
    const float* wfin = (const float*)d_in[15];
    const float* bfin = (const float*)d_in[16];

    float* ws = (float*)d_ws;
    size_t off = 0;
    float* cat  = ws + off; off += (size_t)BATCH * 512 * N_PTS;        // 16 MB
    float* pd   = ws + off; off += (size_t)BATCH * N_PTS * N_PTS;      // 33.5 MB
    float* A    = ws + off; off += (size_t)BATCH * 256 * N_PTS;        // 8 MB (disjoint from pd!)
    float* Bv   = ws + off; off += (size_t)BATCH * 256 * N_PTS;        // 8 MB
    float* xxv  = ws + off; off += (size_t)BATCH * N_PTS;              // 32 KB
    float* pmax = ws + off; off += (size_t)BATCH * N_PTS * 8;
    float* psum = ws + off; off += (size_t)BATCH * N_PTS * 8;
    float* h0   = ws + off; off += (size_t)BATCH * 2048;
    float* h1   = ws + off; off += (size_t)BATCH * 512;
    float* h2   = ws + off; off += (size_t)BATCH * 256;
    int*   idx  = (int*)(ws + off); off += (size_t)BATCH * N_PTS * KNN;
    ushort_t* weh  = (ushort_t*)(ws + off); off += (size_t)(1024 * 512) / 2;        // 1 MB
    ushort_t* catT = (ushort_t*)(ws + off); off += (size_t)BATCH * N_PTS * 512 / 2; // 8 MB
    float* wpt0 = ws + off; off += 3 * 128;
    float* wpt1 = ws + off; off += 64 * 128;
    float* wpt2 = ws + off; off += 64 * 256;
    float* wpt3 = ws + off; off += 128 * 512;

    const int CSTR = 512 * N_PTS;   // cat batch stride
    const int topkBlocks = BATCH * N_PTS / 4;

    // ---- all weight prep in one launch
    prep_kernel<<<866, 256, 0, stream>>>(we, weh, w0, wpt0, w1, wpt1, w2, wpt2, w3, wpt3);

    // ---- block 0: C=3 -> Cout=64 (M2=128)
    xx_kernel<<<dim3(16, BATCH), 64, 0, stream>>>(x, xxv, 3, 3 * N_PTS);
    pdabv_kernel<<<dim3(9, 8, BATCH), 256, 0, stream>>>(x, wpt0, xxv, pd, A, Bv, 3, 64, 3 * N_PTS);
    topk_kernel<<<topkBlocks, 256, 0, stream>>>(pd, idx);
    gmax_kernel<<<dim3(16, 16, BATCH), 256, 0, stream>>>(A, Bv, idx, bn0, cat, 64, CSTR);

    // ---- block 1: C=64 -> Cout=64 (M2=128)
    xx_kernel<<<dim3(16, BATCH), 64, 0, stream>>>(cat, xxv, 64, CSTR);
    pdabv_kernel<<<dim3(9, 8, BATCH), 256, 0, stream>>>(cat, wpt1, xxv, pd, A, Bv, 64, 64, CSTR);
    topk_kernel<<<topkBlocks, 256, 0, stream>>>(pd, idx);
    gmax_kernel<<<dim3(16, 16, BATCH), 256, 0, stream>>>(A, Bv, idx, bn1, cat + 64 * N_PTS, 64, CSTR);

    // ---- block 2: C=64 -> Cout=128 (M2=256)
    xx_kernel<<<dim3(16, BATCH), 64, 0, stream>>>(cat + 64 * N_PTS, xxv, 64, CSTR);
    pdabv_kernel<<<dim3(10, 8, BATCH), 256, 0, stream>>>(cat + 64 * N_PTS, wpt2, xxv, pd, A, Bv, 64, 128, CSTR);
    topk_kernel<<<topkBlocks, 256, 0, stream>>>(pd, idx);
    gmax_kernel<<<dim3(16, 32, BATCH), 256, 0, stream>>>(A, Bv, idx, bn2, cat + 128 * N_PTS, 128, CSTR);

    // ---- block 3: C=128 -> Cout=256 (M2=512)
    xx_kernel<<<dim3(16, BATCH), 64, 0, stream>>>(cat + 128 * N_PTS, xxv, 128, CSTR);
    pdabv_kernel<<<dim3(12, 8, BATCH), 256, 0, stream>>>(cat + 128 * N_PTS, wpt3, xxv, pd, A, Bv, 128, 256, CSTR);
    topk_kernel<<<topkBlocks, 256, 0, stream>>>(pd, idx);
    gmax_kernel<<<dim3(16, 64, BATCH), 256, 0, stream>>>(A, Bv, idx, bn3, cat + 256 * N_PTS, 256, CSTR);

    // ---- cat -> bf16 transposed, then MFMA embedding + pooling
    catT_kernel<<<dim3(16, 8, BATCH), 256, 0, stream>>>(cat, catT);
    gemm6_mfma<<<dim3(8, 8, BATCH), 256, 0, stream>>>(weh, catT, bne, pmax, psum);
    pool_reduce_kernel<<<32, 256, 0, stream>>>(pmax, psum, h0);

    // ---- FC head
    fc_kernel<<<BATCH * 512, 64, 0, stream>>>(h0, wf0, bnf0, nullptr, h1, 2048, 512, 0);
    fc_kernel<<<BATCH * 256, 64, 0, stream>>>(h1, wf1, bnf1, nullptr, h2, 512, 256, 0);
    fc_kernel<<<BATCH * 64, 64, 0, stream>>>(h2, wfin, nullptr, bfin, (float*)d_out, 256, 64, 1);
}

// Round 5
// 350.982 us; speedup vs baseline: 1.3587x; 1.3587x over previous
//
#include <hip/hip_runtime.h>
#include <math.h>

#define N_PTS 1024
#define BATCH 8
#define KNN 20
#define EPSB 1e-5f
#define SLOPE 0.2f

typedef __attribute__((ext_vector_type(8))) short short8;
typedef __attribute__((ext_vector_type(4))) float f32x4;
typedef unsigned short ushort_t;
typedef unsigned long long u64;

__device__ __forceinline__ float lrelu(float y) { return y > 0.f ? y : SLOPE * y; }

__device__ __forceinline__ ushort_t f2bf(float f) {
    union { float f; unsigned u; } v; v.f = f;
    unsigned r = v.u + 0x7FFF + ((v.u >> 16) & 1);   // RNE
    return (ushort_t)(r >> 16);
}

// ---------------- fused weight prep: we->bf16 + 4x W' transforms ----------------
__device__ __forceinline__ void wprep_one(const float* __restrict__ w, float* __restrict__ wpt,
                                          int C, int Cout, int g) {
    int M2 = 2 * Cout;
    if (g >= C * M2) return;
    int c = g / M2, m = g - c * M2;
    float v;
    if (m < Cout) v = w[(size_t)m * 2 * C + c];
    else { int o = m - Cout; v = w[(size_t)o * 2 * C + C + c] - w[(size_t)o * 2 * C + c]; }
    wpt[(size_t)c * M2 + m] = v;
}

__global__ void prep_kernel(const float* __restrict__ we, ushort_t* __restrict__ weh,
                            const float* __restrict__ w0, float* __restrict__ wpt0,
                            const float* __restrict__ w1, float* __restrict__ wpt1,
                            const float* __restrict__ w2, float* __restrict__ wpt2,
                            const float* __restrict__ w3, float* __restrict__ wpt3) {
    int bx = blockIdx.x, tid = threadIdx.x;
    if (bx < 512) {
        int g = bx * 256 + tid;               // 131072 float4 of we
        float4 v = ((const float4*)we)[g];
        ushort4 o;
        o.x = f2bf(v.x); o.y = f2bf(v.y); o.z = f2bf(v.z); o.w = f2bf(v.w);
        ((ushort4*)weh)[g] = o;
    } else if (bx < 514) {
        wprep_one(w0, wpt0, 3, 64, (bx - 512) * 256 + tid);
    } else if (bx < 546) {
        wprep_one(w1, wpt1, 64, 64, (bx - 514) * 256 + tid);
    } else if (bx < 610) {
        wprep_one(w2, wpt2, 64, 128, (bx - 546) * 256 + tid);
    } else {
        wprep_one(w3, wpt3, 128, 256, (bx - 610) * 256 + tid);
    }
}

// ---------------- xx[b][n] = sum_c x^2 ----------------
__global__ void __launch_bounds__(64)
xx_kernel(const float* __restrict__ x, float* __restrict__ xx, int C, int bstride) {
    int b = blockIdx.y;
    int n = blockIdx.x * 64 + threadIdx.x;
    const float* xb = x + (size_t)b * bstride + n;
    float s = 0.f;
    #pragma unroll 4
    for (int c = 0; c < C; c++) { float v = xb[(size_t)c * N_PTS]; s += v * v; }
    xx[b * N_PTS + n] = s;
}

// ---------------- fused pd' + abv (round-0 structure; xx[n] dropped, xx[m] from buffer) ----------------
// bx < pdTiles : pd tile  (m0 = bx*128)            pd'[b,n,m] = 2*dot - xx[m]
// bx >= pdTiles: abv tile (m0 = (bx-pdTiles)*128)  [A;Bv] = W' * x
__global__ void __launch_bounds__(256)
pdabv_kernel(const float* __restrict__ x, const float* __restrict__ wpt,
             const float* __restrict__ xx,
             float* __restrict__ pd, float* __restrict__ A, float* __restrict__ Bv,
             int C, int Cout, int bstride, int pdTiles) {
    int b = blockIdx.z;
    int nt = blockIdx.y;
    int bx = blockIdx.x;
    int tid = threadIdx.x;
    int tx = tid & 15, ty = tid >> 4;
    int n0 = nt * 128;
    __shared__ float sU0[16][128];
    __shared__ float sU1[16][128];
    const float* xb = x + (size_t)b * bstride;
    float acc[8][8] = {};
    if (bx < pdTiles) {
        // ---- pd path ----
        int m0 = bx * 128;
        for (int c0 = 0; c0 < C; c0 += 16) {
            for (int q = 0; q < 2; q++) {
                int f = q * 256 + tid;
                int r = f >> 5, col = (f & 31) * 4;
                int c = c0 + r;
                float4 vn = {0.f, 0.f, 0.f, 0.f}, vm = {0.f, 0.f, 0.f, 0.f};
                if (c < C) {
                    vn = *(const float4*)&xb[(size_t)c * N_PTS + n0 + col];
                    vm = *(const float4*)&xb[(size_t)c * N_PTS + m0 + col];
                }
                *(float4*)&sU0[r][col] = vn;
                *(float4*)&sU1[r][col] = vm;
            }
            __syncthreads();
            for (int k = 0; k < 16; k++) {
                float4 a0 = *(const float4*)&sU0[k][ty * 4];
                float4 a1 = *(const float4*)&sU0[k][64 + ty * 4];
                float4 b0 = *(const float4*)&sU1[k][tx * 4];
                float4 b1 = *(const float4*)&sU1[k][64 + tx * 4];
                float av[8] = {a0.x, a0.y, a0.z, a0.w, a1.x, a1.y, a1.z, a1.w};
                float bw[8] = {b0.x, b0.y, b0.z, b0.w, b1.x, b1.y, b1.z, b1.w};
                for (int i = 0; i < 8; i++)
                    for (int j = 0; j < 8; j++) acc[i][j] += av[i] * bw[j];
            }
            __syncthreads();
        }
        float xm[8];
        const float* xxb = xx + b * N_PTS + m0;
        *(float4*)&xm[0] = *(const float4*)&xxb[tx * 4];
        *(float4*)&xm[4] = *(const float4*)&xxb[64 + tx * 4];
        for (int i = 0; i < 8; i++) {
            int n = n0 + (i >> 2) * 64 + ty * 4 + (i & 3);
            float* prow = pd + ((size_t)(b * N_PTS + n)) * N_PTS;
            for (int jh = 0; jh < 2; jh++) {
                float4 o;
                o.x = 2.f * acc[i][jh * 4 + 0] - xm[jh * 4 + 0];
                o.y = 2.f * acc[i][jh * 4 + 1] - xm[jh * 4 + 1];
                o.z = 2.f * acc[i][jh * 4 + 2] - xm[jh * 4 + 2];
                o.w = 2.f * acc[i][jh * 4 + 3] - xm[jh * 4 + 3];
                *(float4*)&prow[m0 + jh * 64 + tx * 4] = o;
            }
        }
    } else {
        // ---- abv path ----
        int m0 = (bx - pdTiles) * 128;
        int M2 = 2 * Cout;
        for (int c0 = 0; c0 < C; c0 += 16) {
            for (int q = 0; q < 2; q++) {
                int f = q * 256 + tid;
                int r = f >> 5, col = (f & 31) * 4;
                int c = c0 + r;
                float4 vw = {0.f, 0.f, 0.f, 0.f}, vx = {0.f, 0.f, 0.f, 0.f};
                if (c < C) {
                    vw = *(const float4*)&wpt[(size_t)c * M2 + m0 + col];
                    vx = *(const float4*)&xb[(size_t)c * N_PTS + n0 + col];
                }
                *(float4*)&sU0[r][col] = vw;
                *(float4*)&sU1[r][col] = vx;
            }
            __syncthreads();
            for (int k = 0; k < 16; k++) {
                float4 a0 = *(const float4*)&sU0[k][ty * 4];
                float4 a1 = *(const float4*)&sU0[k][64 + ty * 4];
                float4 b0 = *(const float4*)&sU1[k][tx * 4];
                float4 b1 = *(const float4*)&sU1[k][64 + tx * 4];
                float av[8] = {a0.x, a0.y, a0.z, a0.w, a1.x, a1.y, a1.z, a1.w};
                float bw[8] = {b0.x, b0.y, b0.z, b0.w, b1.x, b1.y, b1.z, b1.w};
                for (int i = 0; i < 8; i++)
                    for (int j = 0; j < 8; j++) acc[i][j] += av[i] * bw[j];
            }
            __syncthreads();
        }
        for (int i = 0; i < 8; i++) {
            int rowm = m0 + (i >> 2) * 64 + ty * 4 + (i & 3);
            float* dst = (rowm < Cout) ? (A + ((size_t)b * Cout + rowm) * N_PTS)
                                       : (Bv + ((size_t)b * Cout + rowm - Cout) * N_PTS);
            for (int jh = 0; jh < 2; jh++) {
                float4 o;
                o.x = acc[i][jh * 4 + 0];
                o.y = acc[i][jh * 4 + 1];
                o.z = acc[i][jh * 4 + 2];
                o.w = acc[i][jh * 4 + 3];
                *(float4*)&dst[n0 + jh * 64 + tx * 4] = o;
            }
        }
    }
}

// ---------------- top-20 per row: threshold-compact + bitonic select ----------------
__global__ void __launch_bounds__(256)
topk_kernel(const float* __restrict__ pd, int* __restrict__ idx) {
    int wid = threadIdx.x >> 6;
    int row = blockIdx.x * 4 + wid;          // row = b*N + n
    int lane = threadIdx.x & 63;
    __shared__ u64 Sk[4][64];
    const float* p = pd + (size_t)row * N_PTS;
    float v[16];
    for (int q = 0; q < 4; q++) {
        float4 t = *(const float4*)&p[lane * 16 + q * 4];
        v[q * 4 + 0] = t.x; v[q * 4 + 1] = t.y; v[q * 4 + 2] = t.z; v[q * 4 + 3] = t.w;
    }
    float lmax = v[0];
    #pragma unroll
    for (int j = 1; j < 16; j++) lmax = fmaxf(lmax, v[j]);
    float s = lmax;
    #pragma unroll
    for (int k = 2; k <= 64; k <<= 1) {
        #pragma unroll
        for (int j = k >> 1; j > 0; j >>= 1) {
            float o = __shfl_xor(s, j, 64);
            bool takeMin = (((lane & k) == 0) == ((lane & j) == 0));
            float mn = fminf(s, o), mx = fmaxf(s, o);
            s = takeMin ? mn : mx;
        }
    }
    float tp = __shfl(s, 44, 64);            // 20th largest lane-max
    unsigned hm = 0;
    #pragma unroll
    for (int j = 0; j < 16; j++) hm |= (v[j] >= tp ? 1u : 0u) << j;
    int cnt = __popc(hm);
    int incl = cnt;
    #pragma unroll
    for (int d = 1; d < 64; d <<= 1) {
        int o = __shfl_up(incl, d, 64);
        if (lane >= d) incl += o;
    }
    int total = __shfl(incl, 63, 64);
    int pos = incl - cnt;
    if (total <= 64) {
        #pragma unroll
        for (int j = 0; j < 16; j++) {
            if (hm & (1u << j)) {
                unsigned u = __float_as_uint(v[j]);
                unsigned msk = ((unsigned)((int)u >> 31)) | 0x80000000u;
                Sk[wid][pos] = ((u64)(u ^ msk) << 32) | (unsigned)(1023 - (lane * 16 + j));
                pos++;
            }
        }
        u64 key = (lane < total) ? Sk[wid][lane] : 0ull;
        #pragma unroll
        for (int k = 2; k <= 64; k <<= 1) {
            #pragma unroll
            for (int j = k >> 1; j > 0; j >>= 1) {
                u64 o = __shfl_xor(key, j, 64);
                bool takeMin = (((lane & k) == 0) == ((lane & j) == 0));
                bool sgt = key > o;
                key = (sgt != takeMin) ? key : o;
            }
        }
        if (lane >= 44) {
            int m = 1023 - (int)(unsigned)(key & 0xFFFFFFFFu);
            idx[row * KNN + (63 - lane)] = m;
        }
    } else {
        for (int kk = 0; kk < KNN; kk++) {
            float bv = v[0]; int bj = 0;
            #pragma unroll
            for (int j = 1; j < 16; j++) if (v[j] > bv) { bv = v[j]; bj = j; }
            int bi = lane * 16 + bj;
            for (int d = 32; d > 0; d >>= 1) {
                float ov = __shfl_down(bv, d, 64);
                int oi = __shfl_down(bi, d, 64);
                if (ov > bv || (ov == bv && oi < bi)) { bv = ov; bi = oi; }
            }
            bi = __shfl(bi, 0, 64);
            if ((bi >> 4) == lane) {
                #pragma unroll
                for (int j = 0; j < 16; j++) if (j == (bi & 15)) v[j] = -INFINITY;
            }
            if (lane == 0) idx[row * KNN + kk] = bi;
        }
    }
}

// ---------------- conv0 fused: compute pd row (C=3) inline, then top-20 ----------------
// x slice per batch is 12 KB (L1-resident): no pd materialization for conv0.
// dot/sq accumulation order matches pdabv's k-ascending FMA chain -> bitwise-equal pd'.
__global__ void __launch_bounds__(256)
topk0_kernel(const float* __restrict__ x, int* __restrict__ idx) {
    int wid = threadIdx.x >> 6;
    int row = blockIdx.x * 4 + wid;          // row = b*N + n
    int lane = threadIdx.x & 63;
    __shared__ u64 Sk[4][64];
    int b = row >> 10, n = row & 1023;
    const float* xb = x + (size_t)b * 3 * N_PTS;
    float xr0 = xb[n], xr1 = xb[N_PTS + n], xr2 = xb[2 * N_PTS + n];
    float v[16];
    for (int q = 0; q < 4; q++) {
        int base = lane * 16 + q * 4;
        float4 c0 = *(const float4*)&xb[base];
        float4 c1 = *(const float4*)&xb[N_PTS + base];
        float4 c2 = *(const float4*)&xb[2 * N_PTS + base];
        float a0[4] = {c0.x, c0.y, c0.z, c0.w};
        float a1[4] = {c1.x, c1.y, c1.z, c1.w};
        float a2[4] = {c2.x, c2.y, c2.z, c2.w};
        #pragma unroll
        for (int j = 0; j < 4; j++) {
            float d = 0.f;
            d += xr0 * a0[j]; d += xr1 * a1[j]; d += xr2 * a2[j];
            float sq = 0.f;
            sq += a0[j] * a0[j]; sq += a1[j] * a1[j]; sq += a2[j] * a2[j];
            v[q * 4 + j] = 2.f * d - sq;
        }
    }
    float lmax = v[0];
    #pragma unroll
    for (int j = 1; j < 16; j++) lmax = fmaxf(lmax, v[j]);
    float s = lmax;
    #pragma unroll
    for (int k = 2; k <= 64; k <<= 1) {
        #pragma unroll
        for (int j = k >> 1; j > 0; j >>= 1) {
            float o = __shfl_xor(s, j, 64);
            bool takeMin = (((lane & k) == 0) == ((lane & j) == 0));
            float mn = fminf(s, o), mx = fmaxf(s, o);
            s = takeMin ? mn : mx;
        }
    }
    float tp = __shfl(s, 44, 64);
    unsigned hm = 0;
    #pragma unroll
    for (int j = 0; j < 16; j++) hm |= (v[j] >= tp ? 1u : 0u) << j;
    int cnt = __popc(hm);
    int incl = cnt;
    #pragma unroll
    for (int d = 1; d < 64; d <<= 1) {
        int o = __shfl_up(incl, d, 64);
        if (lane >= d) incl += o;
    }
    int total = __shfl(incl, 63, 64);
    int pos = incl - cnt;
    if (total <= 64) {
        #pragma unroll
        for (int j = 0; j < 16; j++) {
            if (hm & (1u << j)) {
                unsigned u = __float_as_uint(v[j]);
                unsigned msk = ((unsigned)((int)u >> 31)) | 0x80000000u;
                Sk[wid][pos] = ((u64)(u ^ msk) << 32) | (unsigned)(1023 - (lane * 16 + j));
                pos++;
            }
        }
        u64 key = (lane < total) ? Sk[wid][lane] : 0ull;
        #pragma unroll
        for (int k = 2; k <= 64; k <<= 1) {
            #pragma unroll
            for (int j = k >> 1; j > 0; j >>= 1) {
                u64 o = __shfl_xor(key, j, 64);
                bool takeMin = (((lane & k) == 0) == ((lane & j) == 0));
                bool sgt = key > o;
                key = (sgt != takeMin) ? key : o;
            }
        }
        if (lane >= 44) {
            int m = 1023 - (int)(unsigned)(key & 0xFFFFFFFFu);
            idx[row * KNN + (63 - lane)] = m;
        }
    } else {
        for (int kk = 0; kk < KNN; kk++) {
            float bv = v[0]; int bj = 0;
            #pragma unroll
            for (int j = 1; j < 16; j++) if (v[j] > bv) { bv = v[j]; bj = j; }
            int bi = lane * 16 + bj;
            for (int d = 32; d > 0; d >>= 1) {
                float ov = __shfl_down(bv, d, 64);
                int oi = __shfl_down(bi, d, 64);
                if (ov > bv || (ov == bv && oi < bi)) { bv = ov; bi = oi; }
            }
            bi = __shfl(bi, 0, 64);
            if ((bi >> 4) == lane) {
                #pragma unroll
                for (int j = 0; j < 16; j++) if (j == (bi & 15)) v[j] = -INFINITY;
            }
            if (lane == 0) idx[row * KNN + kk] = bi;
        }
    }
}

// ---------------- gmax: LDS-staged gather-max + BN + lrelu ----------------
__global__ void __launch_bounds__(256)
gmax_kernel(const float* __restrict__ A, const float* __restrict__ Bv,
            const int* __restrict__ idx, const float* __restrict__ bnp,
            float* __restrict__ out, int Cout, int outStrideB) {
    int b = blockIdx.z;
    int n0 = blockIdx.x * 64;
    int o0 = blockIdx.y * 4;
    int tid = threadIdx.x;
    __shared__ int sidx[64 * 21];
    __shared__ float sA[4][N_PTS];
    for (int t = tid; t < 64 * KNN; t += 256) {
        int nl = t / KNN, k = t - nl * KNN;
        sidx[nl * 21 + k] = idx[(b * N_PTS + n0) * KNN + t];
    }
    const float* Abase = A + ((size_t)b * Cout + o0) * N_PTS;
    for (int q = 0; q < 4; q++) {
        int f = q * 256 + tid;                 // 1024 float4
        int r = f >> 8, c4 = (f & 255) * 4;
        *(float4*)&sA[r][c4] = *(const float4*)&Abase[(size_t)r * N_PTS + c4];
    }
    __syncthreads();
    int nl = tid & 63, ol = tid >> 6;
    float best = -INFINITY;
    #pragma unroll
    for (int k = 0; k < KNN; k++) {
        int j = sidx[nl * 21 + k];
        best = fmaxf(best, sA[ol][j]);
    }
    int o = o0 + ol;
    int n = n0 + nl;
    float pre = best + Bv[((size_t)b * Cout + o) * N_PTS + n];
    float g = bnp[o], bb = bnp[Cout + o], m = bnp[2 * Cout + o], vv = bnp[3 * Cout + o];
    float scale = g / sqrtf(vv + EPSB);
    out[(size_t)b * outStrideB + (size_t)o * N_PTS + n] = lrelu((pre - m) * scale + bb);
}

// ---------------- cat fp32 [b][c][n] -> catT bf16 [b][n][c] ----------------
__global__ void catT_kernel(const float* __restrict__ cat, ushort_t* __restrict__ catT) {
    int b = blockIdx.z, ct = blockIdx.y, nt = blockIdx.x;
    int tid = threadIdx.x;
    __shared__ float tile[64][65];
    const float* cb = cat + (size_t)b * 512 * N_PTS;
    for (int q = 0; q < 16; q++) {
        int e = q * 256 + tid;
        int c = e >> 6, n = e & 63;
        tile[c][n] = cb[(size_t)(ct * 64 + c) * N_PTS + nt * 64 + n];
    }
    __syncthreads();
    for (int q = 0; q < 16; q++) {
        int e = q * 256 + tid;
        int n = e >> 6, c = e & 63;
        catT[((size_t)b * N_PTS + nt * 64 + n) * 512 + ct * 64 + c] = f2bf(tile[c][n]);
    }
}

// ---------------- embedding GEMM (bf16 MFMA) + bn + lrelu + fused max/sum ----------------
__global__ void __launch_bounds__(256)
gemm6_mfma(const ushort_t* __restrict__ weh, const ushort_t* __restrict__ catT,
           const float* __restrict__ bne,
           float* __restrict__ pmax, float* __restrict__ psum) {
    int b = blockIdx.z, ot = blockIdx.y, nt = blockIdx.x;
    int tid = threadIdx.x;
    int w = tid >> 6, lane = tid & 63, q = lane >> 4, lr = lane & 15;
    int mblk = w >> 1, nblk = w & 1;
    __shared__ __align__(16) ushort_t sA[128 * 40];
    __shared__ __align__(16) ushort_t sB[128 * 40];
    __shared__ float sa[128], sc[128];
    __shared__ float redmax[128][2], redsum[128][2];
    int o0 = ot * 128, n0 = nt * 128;
    if (tid < 128) {
        int o = o0 + tid;
        float g = bne[o], bb = bne[1024 + o], m = bne[2048 + o], vv = bne[3072 + o];
        float scale = g / sqrtf(vv + EPSB);
        sa[tid] = scale; sc[tid] = bb - m * scale;
    }
    f32x4 acc[4][4] = {};
    const ushort_t* cT = catT + (size_t)b * N_PTS * 512;
    int r0 = tid >> 2, s = tid & 3;
    for (int k0 = 0; k0 < 512; k0 += 32) {
        __syncthreads();
        for (int h = 0; h < 2; h++) {
            int r = r0 + h * 64;
            *(short8*)&sA[r * 40 + s * 8] = *(const short8*)(weh + (size_t)(o0 + r) * 512 + k0 + s * 8);
            *(short8*)&sB[r * 40 + s * 8] = *(const short8*)(cT  + (size_t)(n0 + r) * 512 + k0 + s * 8);
        }
        __syncthreads();
        short8 af[4], bfr[4];
        for (int mi = 0; mi < 4; mi++)
            af[mi] = *(const short8*)&sA[(mblk * 64 + mi * 16 + lr) * 40 + q * 8];
        for (int ni = 0; ni < 4; ni++)
            bfr[ni] = *(const short8*)&sB[(nblk * 64 + ni * 16 + lr) * 40 + q * 8];
        for (int mi = 0; mi < 4; mi++)
            for (int ni = 0; ni < 4; ni++)
                acc[mi][ni] = __builtin_amdgcn_mfma_f32_16x16x32_bf16(af[mi], bfr[ni], acc[mi][ni], 0, 0, 0);
    }
    for (int mi = 0; mi < 4; mi++) {
        for (int r = 0; r < 4; r++) {
            int row = mblk * 64 + mi * 16 + q * 4 + r;
            float a = sa[row], c = sc[row];
            float mx = -INFINITY, sm = 0.f;
            for (int ni = 0; ni < 4; ni++) {
                float y = lrelu(acc[mi][ni][r] * a + c);
                mx = fmaxf(mx, y); sm += y;
            }
            for (int msk = 1; msk < 16; msk <<= 1) {
                mx = fmaxf(mx, __shfl_xor(mx, msk, 16));
                sm += __shfl_xor(sm, msk, 16);
            }
            if (lr == 0) { redmax[row][nblk] = mx; redsum[row][nblk] = sm; }
        }
    }
    __syncthreads();
    if (tid < 128) {
        float mx = fmaxf(redmax[tid][0], redmax[tid][1]);
        float sm = redsum[tid][0] + redsum[tid][1];
        int o = o0 + tid;
        pmax[((size_t)(b * 1024 + o)) * 8 + nt] = mx;
        psum[((size_t)(b * 1024 + o)) * 8 + nt] = sm;
    }
}

__global__ void pool_reduce_kernel(const float* __restrict__ pmax, const float* __restrict__ psum,
                                   float* __restrict__ h0) {
    int g = blockIdx.x * 256 + threadIdx.x;  // b*1024 + o
    int b = g >> 10, o = g & 1023;
    float mx = -INFINITY, sm = 0.f;
    for (int t = 0; t < 8; t++) { mx = fmaxf(mx, pmax[g * 8 + t]); sm += psum[g * 8 + t]; }
    h0[(size_t)b * 2048 + o] = mx;
    h0[(size_t)b * 2048 + 1024 + o] = sm * (1.0f / 1024.0f);
}

// ---------------- FC: one wave per output ----------------
__global__ void fc_kernel(const float* __restrict__ in, const float* __restrict__ w,
                          const float* __restrict__ bnp, const float* __restrict__ bias,
                          float* __restrict__ out, int Cin, int Cout, int mode) {
    int blk = blockIdx.x;  // b*Cout + o
    int b = blk / Cout, o = blk % Cout;
    int lane = threadIdx.x;
    const float* inb = in + (size_t)b * Cin;
    const float* wo = w + (size_t)o * Cin;
    float acc = 0.f;
    for (int c = lane; c < Cin; c += 64) acc += inb[c] * wo[c];
    for (int s = 32; s > 0; s >>= 1) acc += __shfl_down(acc, s, 64);
    if (lane == 0) {
        float y = acc;
        if (mode == 0) {
            float g = bnp[o], bb = bnp[Cout + o], m = bnp[2 * Cout + o], vv = bnp[3 * Cout + o];
            y = lrelu((y - m) * (g / sqrtf(vv + EPSB)) + bb);
        } else {
            y += bias[o];
        }
        out[(size_t)b * Cout + o] = y;
    }
}

extern "C" void kernel_launch(void* const* d_in, const int* in_sizes, int n_in,
                              void* d_out, int out_size, void* d_ws, size_t ws_size,
                              hipStream_t stream) {
    const float* x    = (const float*)d_in[0];
    const float* w0   = (const float*)d_in[1];
    const float* w1   = (const float*)d_in[2];
    const float* w2   = (const float*)d_in[3];
    const float* w3   = (const float*)d_in[4];
    const float* bn0  = (const float*)d_in[5];
    const float* bn1  = (const float*)d_in[6];
    const float* bn2  = (const float*)d_in[7];
    const float* bn3  = (const float*)d_in[8];
    const float* we   = (const float*)d_in[9];
    const float* bne  = (const float*)d_in[10];
    const float* wf0  = (const float*)d_in[11];
    const float* bnf0 = (const float*)d_in[12];
    const float* wf1  = (const float*)d_in[13];
    const float* bnf1 = (const float*)d_in[14];
    const float* wfin = (const float*)d_in[15];
    const float* bfin = (const float*)d_in[16];

    float* ws = (float*)d_ws;
    size_t off = 0;
    float* cat  = ws + off; off += (size_t)BATCH * 512 * N_PTS;        // 16 MB
    float* pd   = ws + off; off += (size_t)BATCH * N_PTS * N_PTS;      // 33.5 MB
    float* A    = ws + off; off += (size_t)BATCH * 256 * N_PTS;        // 8 MB (disjoint from pd!)
    float* Bv   = ws + off; off += (size_t)BATCH * 256 * N_PTS;        // 8 MB
    float* xxv  = ws + off; off += (size_t)BATCH * N_PTS;              // 32 KB
    float* pmax = ws + off; off += (size_t)BATCH * N_PTS * 8;
    float* psum = ws + off; off += (size_t)BATCH * N_PTS * 8;
    float* h0   = ws + off; off += (size_t)BATCH * 2048;
    float* h1   = ws + off; off += (size_t)BATCH * 512;
    float* h2   = ws + off; off += (size_t)BATCH * 256;
    int*   idx  = (int*)(ws + off); off += (size_t)BATCH * N_PTS * KNN;
    ushort_t* weh  = (ushort_t*)(ws + off); off += (size_t)(1024 * 512) / 2;        // 1 MB
    ushort_t* catT = (ushort_t*)(ws + off); off += (size_t)BATCH * N_PTS * 512 / 2; // 8 MB
    float* wpt0 = ws + off; off += 3 * 128;
    float* wpt1 = ws + off; off += 64 * 128;
    float* wpt2 = ws + off; off += 64 * 256;
    float* wpt3 = ws + off; off += 128 * 512;

    const int CSTR = 512 * N_PTS;   // cat batch stride
    const int topkBlocks = BATCH * N_PTS / 4;

    // ---- all weight prep in one launch
    prep_kernel<<<866, 256, 0, stream>>>(we, weh, w0, wpt0, w1, wpt1, w2, wpt2, w3, wpt3);

    // ---- block 0: C=3 -> Cout=64. No pd materialization: fused topk0 reads x directly.
    pdabv_kernel<<<dim3(1, 8, BATCH), 256, 0, stream>>>(x, wpt0, xxv, pd, A, Bv, 3, 64, 3 * N_PTS, 0);
    topk0_kernel<<<topkBlocks, 256, 0, stream>>>(x, idx);
    gmax_kernel<<<dim3(16, 16, BATCH), 256, 0, stream>>>(A, Bv, idx, bn0, cat, 64, CSTR);

    // ---- block 1: C=64 -> Cout=64 (M2=128)
    xx_kernel<<<dim3(16, BATCH), 64, 0, stream>>>(cat, xxv, 64, CSTR);
    pdabv_kernel<<<dim3(9, 8, BATCH), 256, 0, stream>>>(cat, wpt1, xxv, pd, A, Bv, 64, 64, CSTR, 8);
    topk_kernel<<<topkBlocks, 256, 0, stream>>>(pd, idx);
    gmax_kernel<<<dim3(16, 16, BATCH), 256, 0, stream>>>(A, Bv, idx, bn1, cat + 64 * N_PTS, 64, CSTR);

    // ---- block 2: C=64 -> Cout=128 (M2=256)
    xx_kernel<<<dim3(16, BATCH), 64, 0, stream>>>(cat + 64 * N_PTS, xxv, 64, CSTR);
    pdabv_kernel<<<dim3(10, 8, BATCH), 256, 0, stream>>>(cat + 64 * N_PTS, wpt2, xxv, pd, A, Bv, 64, 128, CSTR, 8);
    topk_kernel<<<topkBlocks, 256, 0, stream>>>(pd, idx);
    gmax_kernel<<<dim3(16, 32, BATCH), 256, 0, stream>>>(A, Bv, idx, bn2, cat + 128 * N_PTS, 128, CSTR);

    // ---- block 3: C=128 -> Cout=256 (M2=512)
    xx_kernel<<<dim3(16, BATCH), 64, 0, stream>>>(cat + 128 * N_PTS, xxv, 128, CSTR);
    pdabv_kernel<<<dim3(12, 8, BATCH), 256, 0, stream>>>(cat + 128 * N_PTS, wpt3, xxv, pd, A, Bv, 128, 256, CSTR, 8);
    topk_kernel<<<topkBlocks, 256, 0, stream>>>(pd, idx);
    gmax_kernel<<<dim3(16, 64, BATCH), 256, 0, stream>>>(A, Bv, idx, bn3, cat + 256 * N_PTS, 256, CSTR);

    // ---- cat -> bf16 transposed, then MFMA embedding + pooling
    catT_kernel<<<dim3(16, 8, BATCH), 256, 0, stream>>>(cat, catT);
    gemm6_mfma<<<dim3(8, 8, BATCH), 256, 0, stream>>>(weh, catT, bne, pmax, psum);
    pool_reduce_kernel<<<32, 256, 0, stream>>>(pmax, psum, h0);

    // ---- FC head
    fc_kernel<<<BATCH * 512, 64, 0, stream>>>(h0, wf0, bnf0, nullptr, h1, 2048, 512, 0);
    fc_kernel<<<BATCH * 256, 64, 0, stream>>>(h1, wf1, bnf1, nullptr, h2, 512, 256, 0);
    fc_kernel<<<BATCH * 64, 64, 0, stream>>>(h2, wfin, nullptr, bfin, (float*)d_out, 256, 64, 1);
}